// Round 9
// baseline (122.168 us; speedup 1.0000x reference)
//
#include <hip/hip_runtime.h>

#define N_NODES 100000
#define N_EDGES 1600000
#define D_IN    256
#define D_OUT   128

typedef __attribute__((ext_vector_type(8))) short          bf16x8;
typedef __attribute__((ext_vector_type(8))) unsigned short ushort8;
typedef __attribute__((ext_vector_type(4))) float          f32x4;

// f32 -> bf16 (round-to-nearest-even), as raw ushort
__device__ inline unsigned short f2bf(float f) {
  union { float f; unsigned u; } v; v.f = f;
  unsigned r = v.u + 0x7fffu + ((v.u >> 16) & 1u);
  return (unsigned short)(r >> 16);
}
__device__ inline float bf2f(unsigned short u) {
  union { unsigned u; float f; } v; v.u = ((unsigned)u) << 16;
  return v.f;
}

// ---------------------------------------------------------------------------
// Kernel 0: pack W[D_OUT][D_IN] f32 -> bf16 MFMA B-fragment order.
// Frag f = (n*8 + s)*64 + lane holds B[k = s*32+(lane>>4)*8 + j][col = n*16+(lane&15)]
//        = W[col][k], j = 0..7.  (Layout verified correct rounds 4-8.)
// ---------------------------------------------------------------------------
__global__ __launch_bounds__(256) void gcn_packW_kernel(
    const float* __restrict__ W, unsigned short* __restrict__ Wp) {
  int f = blockIdx.x * blockDim.x + threadIdx.x;   // 0..4095
  if (f >= 4096) return;
  int n = f >> 9, s = (f >> 6) & 7, lane = f & 63;
  int col = n * 16 + (lane & 15);
  int k0  = s * 32 + (lane >> 4) * 8;
#pragma unroll
  for (int j = 0; j < 8; ++j)
    Wp[f * 8 + j] = f2bf(W[col * D_IN + k0 + j]);
}

// ---------------------------------------------------------------------------
// Kernel 1: linear, h chunk-split: hc[c][N][64] (c = col>>6) so that the agg
// kernel can gather one FULL 128 B cache line per edge per chunk.
// Structure unchanged from round 8 (16 rows/wave, W-pack staged in LDS,
// ds_read_b128 B-operands, VMEM = coalesced x stream only).
// 512 threads = 8 waves = 128 rows/block; 64 KB LDS -> 2 blocks/CU.
// A layout: lane holds A[row=lane&15][k=(lane>>4)*8 + j].
// C layout: lane holds D[row=(lane>>4)*4 + i][col=lane&15].
// ---------------------------------------------------------------------------
__global__ __launch_bounds__(512) void gcn_linear_mfma_kernel(
    const float* __restrict__ x, const unsigned short* __restrict__ Wp,
    const float* __restrict__ b, unsigned short* __restrict__ h) {
  __shared__ unsigned short lW[32768];   // 64 KiB, fragment-ordered
  const int tid  = threadIdx.x;
  const int lane = tid & 63;
  const int wid  = tid >> 6;             // 0..7
  const int r0   = blockIdx.x * 128 + wid * 16;

  // stage W-pack: 4096 x 16 B, 512 threads -> 8 iters, fully coalesced
#pragma unroll
  for (int i = 0; i < 8; ++i) {
    int idx = i * 512 + tid;
    *(ushort8*)(&lW[idx * 8]) = *(const ushort8*)(Wp + (size_t)idx * 8);
  }
  __syncthreads();

  int arow = r0 + (lane & 15);
  arow = arow < N_NODES ? arow : N_NODES - 1;      // clamp; OOB rows never stored
  const int kg = (lane >> 4) * 8;
  const float* xrow = x + (size_t)arow * D_IN + kg;

  f32x4 acc[8];
#pragma unroll
  for (int n = 0; n < 8; ++n) acc[n] = (f32x4){0.f, 0.f, 0.f, 0.f};

#pragma unroll
  for (int s = 0; s < 8; ++s) {
    float4 a0 = *(const float4*)(xrow + s * 32);
    float4 a1 = *(const float4*)(xrow + s * 32 + 4);
    bf16x8 af;
    af[0] = (short)f2bf(a0.x); af[1] = (short)f2bf(a0.y);
    af[2] = (short)f2bf(a0.z); af[3] = (short)f2bf(a0.w);
    af[4] = (short)f2bf(a1.x); af[5] = (short)f2bf(a1.y);
    af[6] = (short)f2bf(a1.z); af[7] = (short)f2bf(a1.w);
#pragma unroll
    for (int n = 0; n < 8; ++n) {
      bf16x8 bfrag = *(const bf16x8*)(&lW[(size_t)((n * 8 + s) * 64 + lane) * 8]);
      acc[n] = __builtin_amdgcn_mfma_f32_16x16x32_bf16(af, bfrag, acc[n], 0, 0, 0);
    }
  }

  // epilogue: + bias, bf16 store into chunk-split layout hc[n>>2][row][col&63]
  const int col0 = lane & 15;
  const int q4   = (lane >> 4) * 4;
#pragma unroll
  for (int n = 0; n < 8; ++n) {
    const int col = n * 16 + col0;
    const float bias = b[col];
    unsigned short* hc = h + (size_t)(n >> 2) * N_NODES * 64;
    const int c64 = col & 63;
#pragma unroll
    for (int i = 0; i < 4; ++i) {
      const int row = r0 + q4 + i;
      if (row < N_NODES)
        hc[(size_t)row * 64 + c64] = f2bf(acc[n][i] + bias);
    }
  }
}

// ---------------------------------------------------------------------------
// Kernel 2: row_ptr[v] = lower_bound(dst, v) over sorted dst (CSR offsets).
// ---------------------------------------------------------------------------
__global__ __launch_bounds__(256) void gcn_rowptr_kernel(
    const int* __restrict__ dst, int* __restrict__ row_ptr) {
  int v = blockIdx.x * blockDim.x + threadIdx.x;
  if (v > N_NODES) return;
  int lo = 0, hi = N_EDGES;
  while (lo < hi) {
    int mid = (lo + hi) >> 1;
    if (dst[mid] < v) lo = mid + 1; else hi = mid;
  }
  row_ptr[v] = lo;
}

// ---------------------------------------------------------------------------
// Kernel 3: 64-dim-chunked, XCD-pinned segment sum.
//   out[v][64c .. 64c+63] = sum_e hc[c][src[e]][:] * w[e]
// chunk c = blockIdx & 1: round-robin block->XCD dispatch pins chunk 0 to
// even XCDs, chunk 1 to odd -> per-L2 h working set 25.6 -> 12.8 MB.
// CRITICAL (round-7 lesson): each edge-gather is one FULL 128 B cache line
// (8 lanes x 16 B), so L2<-L3 fill granularity is 100% used.
// One wave per (node, chunk): 8 edge slots x 8 lanes, 2 edges/slot/iter
// (16 edges/iter = mean degree); shfl_xor(8,16,32) reduce; 2x float4 store
// by slot 0 (256 B contiguous). Atomic-free, deterministic.
// ---------------------------------------------------------------------------
__global__ __launch_bounds__(256) void gcn_agg_kernel(
    const unsigned short* __restrict__ h, const int* __restrict__ src,
    const float* __restrict__ w, const int* __restrict__ rp,
    float* __restrict__ out) {
  const int chunk = blockIdx.x & 1;
  const int node  = ((blockIdx.x >> 1) << 2) + (threadIdx.x >> 6);
  if (node >= N_NODES) return;
  const int lane = threadIdx.x & 63;
  const int slot = lane >> 3;        // edge slot 0..7
  const int dg   = (lane & 7) << 3;  // dim offset 0,8,...,56 within chunk
  const unsigned short* hc = h + (size_t)chunk * N_NODES * 64;

  const int s = rp[node], e = rp[node + 1];
  float acc[8];
#pragma unroll
  for (int j = 0; j < 8; ++j) acc[j] = 0.f;

  for (int base = s; base < e; base += 16) {
    const int i0 = base + (slot << 1);   // slot-uniform
    if (i0 < e) {
      int   sv[2];
      float wv[2];
#pragma unroll
      for (int j = 0; j < 2; ++j) {
        int  i = i0 + j;
        bool valid = (i < e);
        int  ic = valid ? i : i0;        // i0 is valid here
        sv[j] = src[ic];
        wv[j] = valid ? w[ic] : 0.f;
      }
      ushort8 hv[2];
#pragma unroll
      for (int j = 0; j < 2; ++j)
        hv[j] = *(const ushort8*)(hc + (size_t)sv[j] * 64 + dg);
#pragma unroll
      for (int j = 0; j < 2; ++j)
#pragma unroll
        for (int k = 0; k < 8; ++k)
          acc[k] += bf2f(hv[j][k]) * wv[j];
    }
  }

#pragma unroll
  for (int j = 0; j < 8; ++j) {
    acc[j] += __shfl_xor(acc[j], 8);
    acc[j] += __shfl_xor(acc[j], 16);
    acc[j] += __shfl_xor(acc[j], 32);
  }

  if (slot == 0) {
    float4 o0 = {acc[0], acc[1], acc[2], acc[3]};
    float4 o1 = {acc[4], acc[5], acc[6], acc[7]};
    float* op = out + (size_t)node * D_OUT + chunk * 64 + dg;
    *(float4*)(op)     = o0;
    *(float4*)(op + 4) = o1;
  }
}

extern "C" void kernel_launch(void* const* d_in, const int* in_sizes, int n_in,
                              void* d_out, int out_size, void* d_ws, size_t ws_size,
                              hipStream_t stream) {
  const float* x   = (const float*)d_in[0];
  const int*   src = (const int*)d_in[1];
  const int*   dst = (const int*)d_in[2];
  const float* w   = (const float*)d_in[3];
  const float* W   = (const float*)d_in[4];
  const float* b   = (const float*)d_in[5];
  float* out = (float*)d_out;

  // workspace: Wpack (64 KB) | h bf16 2x[N][64] (25.6 MB) | row_ptr (400 KB)
  unsigned short* Wp = (unsigned short*)d_ws;
  unsigned short* h  = (unsigned short*)((char*)d_ws + 65536);
  int* row_ptr = (int*)((char*)d_ws + 65536 + (size_t)N_NODES * D_OUT * sizeof(unsigned short));

  // 0) pack W -> bf16 fragment order
  gcn_packW_kernel<<<16, 256, 0, stream>>>(W, Wp);
  // 1) CSR offsets (independent of h -> launch before the big GEMM)
  gcn_rowptr_kernel<<<(N_NODES + 1 + 255) / 256, 256, 0, stream>>>(dst, row_ptr);
  // 2) h = bf16(x @ W^T + b), chunk-split layout, 128 rows/block
  gcn_linear_mfma_kernel<<<(N_NODES + 127) / 128, 512, 0, stream>>>(x, Wp, b, h);
  // 3) XCD-pinned 64-dim-chunked segment-sum: 2 chunks x 25000 node-blocks
  gcn_agg_kernel<<<2 * (N_NODES / 4), 256, 0, stream>>>(h, src, w, row_ptr, out);
}

// Round 10
// 116.872 us; speedup vs baseline: 1.0453x; 1.0453x over previous
//
#include <hip/hip_runtime.h>

#define N_NODES 100000
#define N_EDGES 1600000
#define D_IN    256
#define D_OUT   128

typedef __attribute__((ext_vector_type(8))) short          bf16x8;
typedef __attribute__((ext_vector_type(8))) unsigned short ushort8;
typedef __attribute__((ext_vector_type(4))) float          f32x4;

// f32 -> bf16 (round-to-nearest-even), as raw ushort
__device__ inline unsigned short f2bf(float f) {
  union { float f; unsigned u; } v; v.f = f;
  unsigned r = v.u + 0x7fffu + ((v.u >> 16) & 1u);
  return (unsigned short)(r >> 16);
}
__device__ inline float bf2f(unsigned short u) {
  union { unsigned u; float f; } v; v.u = ((unsigned)u) << 16;
  return v.f;
}

// ---------------------------------------------------------------------------
// Kernel 0: pack W[D_OUT][D_IN] f32 -> bf16 MFMA B-fragment order.
// Frag f = (n*8 + s)*64 + lane holds B[k = s*32+(lane>>4)*8 + j][col = n*16+(lane&15)]
//        = W[col][k], j = 0..7.  (Layout verified correct rounds 4-9.)
// ---------------------------------------------------------------------------
__global__ __launch_bounds__(256) void gcn_packW_kernel(
    const float* __restrict__ W, unsigned short* __restrict__ Wp) {
  int f = blockIdx.x * blockDim.x + threadIdx.x;   // 0..4095
  if (f >= 4096) return;
  int n = f >> 9, s = (f >> 6) & 7, lane = f & 63;
  int col = n * 16 + (lane & 15);
  int k0  = s * 32 + (lane >> 4) * 8;
#pragma unroll
  for (int j = 0; j < 8; ++j)
    Wp[f * 8 + j] = f2bf(W[col * D_IN + k0 + j]);
}

// ---------------------------------------------------------------------------
// Kernel 1: h[N][128] (bf16) = bf16(x) @ W^T + b via mfma_f32_16x16x32_bf16.
// Round-10 changes vs round-8 (both targeting the x-stream, the only real
// traffic: 102 MB read + 26 MB write -> ~20 us floor):
//  (a) 256-thread blocks (4 waves x 16 rows = 64 rows/block): 1563 blocks
//      at 2 blocks/CU = 3.05 generations -> tail ~2% (was 1.53 gen, ~35%).
//  (b) explicit 2-stage pipeline over the 8 k-steps: prefetch step s+1's
//      two float4 before computing step s (named regs, static indexing).
// W-pack still staged in LDS (64 KB): B-operand chain = ds_read_b128,
// VMEM carries only the coalesced x stream.
// A layout: lane holds A[row=lane&15][k=(lane>>4)*8 + j].
// C layout: lane holds D[row=(lane>>4)*4 + i][col=lane&15].
// ---------------------------------------------------------------------------
__global__ __launch_bounds__(256) void gcn_linear_mfma_kernel(
    const float* __restrict__ x, const unsigned short* __restrict__ Wp,
    const float* __restrict__ b, unsigned short* __restrict__ h) {
  __shared__ unsigned short lW[32768];   // 64 KiB, fragment-ordered
  const int tid  = threadIdx.x;
  const int lane = tid & 63;
  const int wid  = tid >> 6;             // 0..3
  const int r0   = blockIdx.x * 64 + wid * 16;

  // stage W-pack: 4096 x 16 B, 256 threads -> 16 iters, fully coalesced
#pragma unroll
  for (int i = 0; i < 16; ++i) {
    int idx = i * 256 + tid;
    *(ushort8*)(&lW[idx * 8]) = *(const ushort8*)(Wp + (size_t)idx * 8);
  }
  __syncthreads();

  int arow = r0 + (lane & 15);
  arow = arow < N_NODES ? arow : N_NODES - 1;      // clamp; OOB rows never stored
  const int kg = (lane >> 4) * 8;
  const float* xrow = x + (size_t)arow * D_IN + kg;

  f32x4 acc[8];
#pragma unroll
  for (int n = 0; n < 8; ++n) acc[n] = (f32x4){0.f, 0.f, 0.f, 0.f};

  // 2-stage pipeline: cur = step s data, nxt = step s+1 (prefetched)
  float4 c0 = *(const float4*)(xrow);
  float4 c1 = *(const float4*)(xrow + 4);
#pragma unroll
  for (int s = 0; s < 8; ++s) {
    float4 n0, n1;
    if (s < 7) {
      n0 = *(const float4*)(xrow + (s + 1) * 32);
      n1 = *(const float4*)(xrow + (s + 1) * 32 + 4);
    }
    bf16x8 af;
    af[0] = (short)f2bf(c0.x); af[1] = (short)f2bf(c0.y);
    af[2] = (short)f2bf(c0.z); af[3] = (short)f2bf(c0.w);
    af[4] = (short)f2bf(c1.x); af[5] = (short)f2bf(c1.y);
    af[6] = (short)f2bf(c1.z); af[7] = (short)f2bf(c1.w);
#pragma unroll
    for (int n = 0; n < 8; ++n) {
      bf16x8 bfrag = *(const bf16x8*)(&lW[(size_t)((n * 8 + s) * 64 + lane) * 8]);
      acc[n] = __builtin_amdgcn_mfma_f32_16x16x32_bf16(af, bfrag, acc[n], 0, 0, 0);
    }
    c0 = n0; c1 = n1;
  }

  // epilogue: + bias, bf16 store (scalar 2B stores, 16-lane col groups
  // coalesce to 32B segments; WRITE_SIZE confirmed efficient rounds 4-8)
  const int col0 = lane & 15;
  const int q4   = (lane >> 4) * 4;
#pragma unroll
  for (int n = 0; n < 8; ++n) {
    const int col = n * 16 + col0;
    const float bias = b[col];
#pragma unroll
    for (int i = 0; i < 4; ++i) {
      const int row = r0 + q4 + i;
      if (row < N_NODES)
        h[(size_t)row * D_OUT + col] = f2bf(acc[n][i] + bias);
    }
  }
}

// ---------------------------------------------------------------------------
// Kernel 2: row_ptr[v] = lower_bound(dst, v) over sorted dst (CSR offsets).
// ---------------------------------------------------------------------------
__global__ __launch_bounds__(256) void gcn_rowptr_kernel(
    const int* __restrict__ dst, int* __restrict__ row_ptr) {
  int v = blockIdx.x * blockDim.x + threadIdx.x;
  if (v > N_NODES) return;
  int lo = 0, hi = N_EDGES;
  while (lo < hi) {
    int mid = (lo + hi) >> 1;
    if (dst[mid] < v) lo = mid + 1; else hi = mid;
  }
  row_ptr[v] = lo;
}

// ---------------------------------------------------------------------------
// Kernel 3 (round-8 structure, the measured optimum — rounds 7/9 proved both
// finer-grained chunkings regress): one WAVE per node, 4 lane-groups x 16
// lanes, 4 edges per group per iteration (16 edges/wave = mean degree).
// Per-edge gather = FULL 256 B row (2 complete cache lines, zero fill waste).
// shfl_xor(16,32) cross-group reduce, float4 store. Atomic-free.
// Structural wall: 410 MB gather demand at ~6.1 TB/s mixed L2/L3/HBM; FETCH
// ~185 MB ~= 8 XCDs x 25.6 MB (each L2 pulls h once) -> ~67 us.
// ---------------------------------------------------------------------------
__global__ __launch_bounds__(256) void gcn_agg_kernel(
    const unsigned short* __restrict__ h, const int* __restrict__ src,
    const float* __restrict__ w, const int* __restrict__ rp,
    float* __restrict__ out) {
  const int node = (blockIdx.x << 2) + (threadIdx.x >> 6);
  if (node >= N_NODES) return;
  const int lane = threadIdx.x & 63;
  const int g  = lane >> 4;          // group 0..3
  const int dg = (lane & 15) << 3;   // dim offset 0,8,...,120

  const int s = rp[node], e = rp[node + 1];
  float acc[8];
#pragma unroll
  for (int j = 0; j < 8; ++j) acc[j] = 0.f;

  for (int base = s; base < e; base += 16) {
    const int i0 = base + (g << 2);      // group-uniform
    if (i0 < e) {
      int   sv[4];
      float wv[4];
#pragma unroll
      for (int j = 0; j < 4; ++j) {
        int  i = i0 + j;
        bool valid = (i < e);
        int  ic = valid ? i : i0;        // i0 is valid here
        sv[j] = src[ic];
        wv[j] = valid ? w[ic] : 0.f;
      }
      ushort8 hv[4];
#pragma unroll
      for (int j = 0; j < 4; ++j)
        hv[j] = *(const ushort8*)(h + (size_t)sv[j] * D_OUT + dg);
#pragma unroll
      for (int j = 0; j < 4; ++j)
#pragma unroll
        for (int k = 0; k < 8; ++k)
          acc[k] += bf2f(hv[j][k]) * wv[j];
    }
  }

#pragma unroll
  for (int j = 0; j < 8; ++j) acc[j] += __shfl_xor(acc[j], 16);
#pragma unroll
  for (int j = 0; j < 8; ++j) acc[j] += __shfl_xor(acc[j], 32);

  if (g == 0) {
    float4 o0 = {acc[0], acc[1], acc[2], acc[3]};
    float4 o1 = {acc[4], acc[5], acc[6], acc[7]};
    float* op = out + (size_t)node * D_OUT + dg;
    *(float4*)(op)     = o0;
    *(float4*)(op + 4) = o1;
  }
}

extern "C" void kernel_launch(void* const* d_in, const int* in_sizes, int n_in,
                              void* d_out, int out_size, void* d_ws, size_t ws_size,
                              hipStream_t stream) {
  const float* x   = (const float*)d_in[0];
  const int*   src = (const int*)d_in[1];
  const int*   dst = (const int*)d_in[2];
  const float* w   = (const float*)d_in[3];
  const float* W   = (const float*)d_in[4];
  const float* b   = (const float*)d_in[5];
  float* out = (float*)d_out;

  // workspace: Wpack (64 KB) | h bf16 [N][128] (25.6 MB) | row_ptr (400 KB)
  unsigned short* Wp = (unsigned short*)d_ws;
  unsigned short* h  = (unsigned short*)((char*)d_ws + 65536);
  int* row_ptr = (int*)((char*)d_ws + 65536 + (size_t)N_NODES * D_OUT * sizeof(unsigned short));

  // 0) pack W -> bf16 fragment order
  gcn_packW_kernel<<<16, 256, 0, stream>>>(W, Wp);
  // 1) CSR offsets (independent of h)
  gcn_rowptr_kernel<<<(N_NODES + 1 + 255) / 256, 256, 0, stream>>>(dst, row_ptr);
  // 2) h = bf16(x @ W^T + b), 64 rows/block, LDS-staged W, pipelined x
  gcn_linear_mfma_kernel<<<(N_NODES + 63) / 64, 256, 0, stream>>>(x, Wp, b, h);
  // 3) segment-sum of w-scaled gathered rows (round-8 structure)
  gcn_agg_kernel<<<N_NODES / 4, 256, 0, stream>>>(h, src, w, row_ptr, out);
}

// Round 11
// 110.554 us; speedup vs baseline: 1.1051x; 1.0572x over previous
//
#include <hip/hip_runtime.h>

#define N_NODES 100000
#define N_EDGES 1600000
#define D_IN    256
#define D_OUT   128

typedef __attribute__((ext_vector_type(8))) short          bf16x8;
typedef __attribute__((ext_vector_type(8))) unsigned short ushort8;
typedef __attribute__((ext_vector_type(4))) float          f32x4;

// f32 -> bf16 (round-to-nearest-even), as raw ushort
__device__ inline unsigned short f2bf(float f) {
  union { float f; unsigned u; } v; v.f = f;
  unsigned r = v.u + 0x7fffu + ((v.u >> 16) & 1u);
  return (unsigned short)(r >> 16);
}
__device__ inline float bf2f(unsigned short u) {
  union { unsigned u; float f; } v; v.u = ((unsigned)u) << 16;
  return v.f;
}

// ---------------------------------------------------------------------------
// Kernel 0 (merged): [threads 0..4095] pack W f32 -> bf16 MFMA B-fragment
// order (frag f = (n*8+s)*64+lane holds W[col=n*16+(lane&15)][k=s*32+(lane>>4)*8+j],
// layout verified rounds 4-10); [threads 4096..] row_ptr[v] = lower_bound(dst,v).
// ---------------------------------------------------------------------------
__global__ __launch_bounds__(256) void gcn_prep_kernel(
    const float* __restrict__ W, unsigned short* __restrict__ Wp,
    const int* __restrict__ dst, int* __restrict__ row_ptr) {
  int gid = blockIdx.x * blockDim.x + threadIdx.x;
  if (gid < 4096) {
    int f = gid;
    int n = f >> 9, s = (f >> 6) & 7, lane = f & 63;
    int col = n * 16 + (lane & 15);
    int k0  = s * 32 + (lane >> 4) * 8;
#pragma unroll
    for (int j = 0; j < 8; ++j)
      Wp[f * 8 + j] = f2bf(W[col * D_IN + k0 + j]);
  } else {
    int v = gid - 4096;
    if (v > N_NODES) return;
    int lo = 0, hi = N_EDGES;
    while (lo < hi) {
      int mid = (lo + hi) >> 1;
      if (dst[mid] < v) lo = mid + 1; else hi = mid;
    }
    row_ptr[v] = lo;
  }
}

// ---------------------------------------------------------------------------
// Kernel 1: h[N][128] (bf16) = bf16(x) @ W^T + b, COLUMN-SPLIT for occupancy.
// Round-6 counters proved x is L3-resident (FETCH 50MB < x's 102MB), so the
// linear is latency-bound, and 64KB LDS capped us at 2 blocks/CU (50% occ).
// Each block now stages HALF the W-pack (32 KB) and computes 128 rows x 64
// cols; grid doubles (x re-read is L3-absorbed). 32KB x 4 blocks/CU x 512
// thr = 2048 thr/CU = 100% occupancy; acc halves to 16 VGPR.
// Epilogue: reuse the W LDS buffer to repack each wave's 16x64 output so the
// h store is 2 full-cache-line ushort8 stores (64-col half of a row = exactly
// one 128B line) instead of 32 scattered 2B stores.
// A layout: lane holds A[row=lane&15][k=(lane>>4)*8 + j].
// C layout: lane holds D[row=(lane>>4)*4 + i][col=lane&15].
// ---------------------------------------------------------------------------
__global__ __launch_bounds__(512, 8) void gcn_linear_mfma_kernel(
    const float* __restrict__ x, const unsigned short* __restrict__ Wp,
    const float* __restrict__ b, unsigned short* __restrict__ h) {
  __shared__ unsigned short lW[16384];   // 32 KiB: one 64-col half of W-pack
  const int tid  = threadIdx.x;
  const int lane = tid & 63;
  const int wid  = tid >> 6;             // 0..7
  const int half = blockIdx.x & 1;       // col half: 0 -> cols 0..63, 1 -> 64..127
  const int r0   = (blockIdx.x >> 1) * 128 + wid * 16;

  // stage half W-pack: 2048 frags x 16 B, 512 threads -> 4 iters, coalesced
#pragma unroll
  for (int i = 0; i < 4; ++i) {
    int idx = i * 512 + tid;             // 0..2047
    *(ushort8*)(&lW[idx * 8]) =
        *(const ushort8*)(Wp + ((size_t)(half * 2048 + idx)) * 8);
  }
  __syncthreads();

  int arow = r0 + (lane & 15);
  arow = arow < N_NODES ? arow : N_NODES - 1;      // clamp; OOB rows never stored
  const int kg = (lane >> 4) * 8;
  const float* xrow = x + (size_t)arow * D_IN + kg;

  f32x4 acc[4];
#pragma unroll
  for (int n = 0; n < 4; ++n) acc[n] = (f32x4){0.f, 0.f, 0.f, 0.f};

#pragma unroll
  for (int s = 0; s < 8; ++s) {
    float4 a0 = *(const float4*)(xrow + s * 32);
    float4 a1 = *(const float4*)(xrow + s * 32 + 4);
    bf16x8 af;
    af[0] = (short)f2bf(a0.x); af[1] = (short)f2bf(a0.y);
    af[2] = (short)f2bf(a0.z); af[3] = (short)f2bf(a0.w);
    af[4] = (short)f2bf(a1.x); af[5] = (short)f2bf(a1.y);
    af[6] = (short)f2bf(a1.z); af[7] = (short)f2bf(a1.w);
#pragma unroll
    for (int n = 0; n < 4; ++n) {
      bf16x8 bfrag = *(const bf16x8*)(&lW[(size_t)((n * 8 + s) * 64 + lane) * 8]);
      acc[n] = __builtin_amdgcn_mfma_f32_16x16x32_bf16(af, bfrag, acc[n], 0, 0, 0);
    }
  }

  // ---- epilogue: +bias, repack through LDS (reuse lW), full-line stores ----
  __syncthreads();                       // all waves done reading W
  unsigned short* my = &lW[wid * 1024];  // 16 rows x 64 cols bf16 = 2 KB/wave
  const int col0 = lane & 15;
  const int q4   = (lane >> 4) * 4;
#pragma unroll
  for (int n = 0; n < 4; ++n) {
    const float bias = b[half * 64 + n * 16 + col0];
#pragma unroll
    for (int i = 0; i < 4; ++i)
      my[(q4 + i) * 64 + n * 16 + col0] = f2bf(acc[n][i] + bias);
  }
  __syncthreads();                       // order ds_write -> ds_read (block-wide, cheap)
#pragma unroll
  for (int j = 0; j < 2; ++j) {
    const int flat = j * 64 + lane;      // 0..127 sixteen-byte units
    const int row  = flat >> 3;          // 0..15
    const int cin  = (flat & 7) * 8;     // 0,8,...,56
    if (r0 + row < N_NODES) {
      ushort8 v = *(const ushort8*)(&my[(size_t)flat * 8]);
      *(ushort8*)(&h[(size_t)(r0 + row) * D_OUT + half * 64 + cin]) = v;
    }
  }
}

// ---------------------------------------------------------------------------
// Kernel 3 (round-8 structure, measured optimum — rounds 7/9 proved finer
// chunkings regress): one WAVE per node, 4 lane-groups x 16 lanes, 4 edges
// per group per iteration (16 edges/wave = mean degree). Per-edge gather =
// FULL 256 B row (2 complete cache lines, zero fill waste). shfl_xor(16,32)
// cross-group reduce, float4 store. Atomic-free, deterministic.
// Structural wall: 410 MB gather demand, FETCH ~185 MB ~= 8 XCDs x 25.6 MB
// (each L2 pulls h once) -> ~67 us at the mixed L2/L3 service rate.
// ---------------------------------------------------------------------------
__global__ __launch_bounds__(256) void gcn_agg_kernel(
    const unsigned short* __restrict__ h, const int* __restrict__ src,
    const float* __restrict__ w, const int* __restrict__ rp,
    float* __restrict__ out) {
  const int node = (blockIdx.x << 2) + (threadIdx.x >> 6);
  if (node >= N_NODES) return;
  const int lane = threadIdx.x & 63;
  const int g  = lane >> 4;          // group 0..3
  const int dg = (lane & 15) << 3;   // dim offset 0,8,...,120

  const int s = rp[node], e = rp[node + 1];
  float acc[8];
#pragma unroll
  for (int j = 0; j < 8; ++j) acc[j] = 0.f;

  for (int base = s; base < e; base += 16) {
    const int i0 = base + (g << 2);      // group-uniform
    if (i0 < e) {
      int   sv[4];
      float wv[4];
#pragma unroll
      for (int j = 0; j < 4; ++j) {
        int  i = i0 + j;
        bool valid = (i < e);
        int  ic = valid ? i : i0;        // i0 is valid here
        sv[j] = src[ic];
        wv[j] = valid ? w[ic] : 0.f;
      }
      ushort8 hv[4];
#pragma unroll
      for (int j = 0; j < 4; ++j)
        hv[j] = *(const ushort8*)(h + (size_t)sv[j] * D_OUT + dg);
#pragma unroll
      for (int j = 0; j < 4; ++j)
#pragma unroll
        for (int k = 0; k < 8; ++k)
          acc[k] += bf2f(hv[j][k]) * wv[j];
    }
  }

#pragma unroll
  for (int j = 0; j < 8; ++j) acc[j] += __shfl_xor(acc[j], 16);
#pragma unroll
  for (int j = 0; j < 8; ++j) acc[j] += __shfl_xor(acc[j], 32);

  if (g == 0) {
    float4 o0 = {acc[0], acc[1], acc[2], acc[3]};
    float4 o1 = {acc[4], acc[5], acc[6], acc[7]};
    float* op = out + (size_t)node * D_OUT + dg;
    *(float4*)(op)     = o0;
    *(float4*)(op + 4) = o1;
  }
}

extern "C" void kernel_launch(void* const* d_in, const int* in_sizes, int n_in,
                              void* d_out, int out_size, void* d_ws, size_t ws_size,
                              hipStream_t stream) {
  const float* x   = (const float*)d_in[0];
  const int*   src = (const int*)d_in[1];
  const int*   dst = (const int*)d_in[2];
  const float* w   = (const float*)d_in[3];
  const float* W   = (const float*)d_in[4];
  const float* b   = (const float*)d_in[5];
  float* out = (float*)d_out;

  // workspace: Wpack (64 KB) | h bf16 [N][128] (25.6 MB) | row_ptr (400 KB)
  unsigned short* Wp = (unsigned short*)d_ws;
  unsigned short* h  = (unsigned short*)((char*)d_ws + 65536);
  int* row_ptr = (int*)((char*)d_ws + 65536 + (size_t)N_NODES * D_OUT * sizeof(unsigned short));

  // 0) pack W + CSR offsets (merged, independent of h)
  gcn_prep_kernel<<<(4096 + N_NODES + 1 + 255) / 256, 256, 0, stream>>>(W, Wp, dst, row_ptr);
  // 1) h = bf16(x @ W^T + b): 128 rows x 64 cols per block, 4 blocks/CU
  gcn_linear_mfma_kernel<<<2 * ((N_NODES + 127) / 128), 512, 0, stream>>>(x, Wp, b, h);
  // 2) segment-sum of w-scaled gathered rows (round-8 structure)
  gcn_agg_kernel<<<N_NODES / 4, 256, 0, stream>>>(h, src, w, row_ptr, out);
}